// Round 3
// baseline (382.799 us; speedup 1.0000x reference)
//
#include <hip/hip_runtime.h>
#include <hip/hip_bf16.h>

// Problem constants: B=8, C=192, H=W=128, NH=6, HD=32, N=16384
constexpr int B   = 8;
constexpr int Cc  = 192;
constexpr int H   = 128;
constexpr int Wd  = 128;
constexpr int NH  = 6;
constexpr int HD  = 32;           // channels per head
constexpr int HW  = H * Wd;       // 16384

typedef short s16x8 __attribute__((ext_vector_type(8)));
typedef float f32x16 __attribute__((ext_vector_type(16)));

// Workspace layout (bytes):
//   v    : [B][192][HW] bf16           =  50,331,648
//   attn : [B][NH][32][32] fp32        =     196,608
//   ssq  : [2][B][Cc] fp32 (q then k)  =      12,288
//   M    : [B][192][192] bf16 ([o][c]) =     589,824
constexpr size_t OFF_V    = 0;
constexpr size_t OFF_ATTN = 50331648ULL;
constexpr size_t OFF_SSQ  = OFF_ATTN + 196608ULL;
constexpr size_t OFF_M    = OFF_SSQ + 12288ULL;
constexpr int    N_ZERO   = (196608 + 12288) / 4;   // attn+ssq floats

__device__ inline unsigned short f2bf(float f) {
    __hip_bfloat16 h = __float2bfloat16(f);
    return *(unsigned short*)&h;
}

__global__ void zero_kernel(float* __restrict__ p, int n) {
    int i = blockIdx.x * 256 + threadIdx.x;
    if (i < n) p[i] = 0.f;
}

// ---------------------------------------------------------------------------
// K1a: fused grouped-3x3-conv (q,k) + channel-Gram (q@k^T) per (b,h,4-row tile).
// Pipelined: strip s+1's global loads are issued during strip s's conv phase
// (T14 issue-early/write-late), so HBM latency hides under VALU work.
// grid: (H/4=32, NH, B), block 256 = 32 ch x 8 col-quads, 4 waves.
// LDS: 22.5KB x-stage + 2*8KB frags = 38.5KB -> 4 blocks/CU.
// ---------------------------------------------------------------------------

// read 6 conv-window floats (cols 4q8+3 .. 4q8+8 of a 40-float LDS row)
__device__ __forceinline__ void ld6(const float* __restrict__ base, int r,
                                    int q8, float (&e)[6]) {
    const float* p = base + r * 40 + q8 * 4;     // 16B aligned
    float4 a = *(const float4*)p;
    float4 bq = *(const float4*)(p + 4);
    float2 cd = *(const float2*)(p + 8);
    e[0] = a.w; e[1] = bq.x; e[2] = bq.y; e[3] = bq.z; e[4] = bq.w; e[5] = cd.x;
}

// 4-row x 4-col conv for one output channel from staged LDS; pack bf16x4 into
// fragment-native frag[g=4y+(q8>>1)][ch][8]. Returns sum of squares.
__device__ __forceinline__ float conv_lds(
    const float* __restrict__ base, const float (&wr)[9], float br,
    int q8, int ch, unsigned short* __restrict__ frag)
{
    float rv[3][6];
    ld6(base, 0, q8, rv[0]);
    ld6(base, 1, q8, rv[1]);
    float ss = 0.f;
#pragma unroll
    for (int y = 0; y < 4; ++y) {
        ld6(base, y + 2, q8, rv[(y + 2) % 3]);
        const float* r0 = rv[y % 3];
        const float* r1 = rv[(y + 1) % 3];
        const float* r2 = rv[(y + 2) % 3];
        float o[4];
#pragma unroll
        for (int xx = 0; xx < 4; ++xx) {
            o[xx] = br
                + wr[0] * r0[xx] + wr[1] * r0[xx + 1] + wr[2] * r0[xx + 2]
                + wr[3] * r1[xx] + wr[4] * r1[xx + 1] + wr[5] * r1[xx + 2]
                + wr[6] * r2[xx] + wr[7] * r2[xx + 1] + wr[8] * r2[xx + 2];
        }
        ss += o[0] * o[0] + o[1] * o[1] + o[2] * o[2] + o[3] * o[3];
        ushort4 pk = make_ushort4(f2bf(o[0]), f2bf(o[1]), f2bf(o[2]), f2bf(o[3]));
        int g = 4 * y + (q8 >> 1);
        *(ushort4*)(frag + ((g * 32 + ch) << 3) + ((q8 & 1) << 2)) = pk;
    }
    return ss;
}

__device__ __forceinline__ void fetch_strip(
    const float* const (&srcp)[6], const int (&colb)[6], int s, float4 (&pf)[6])
{
#pragma unroll
    for (int j = 0; j < 6; ++j) {
        int col = s * 32 + colb[j];
        const float* p = srcp[j];
        float4 v = make_float4(0.f, 0.f, 0.f, 0.f);
        if (p != nullptr && (unsigned)col <= 124u)
            v = *(const float4*)(p + col);
        pf[j] = v;
    }
}

__global__ __launch_bounds__(256, 4) void fused_conv_qk(
    const float* __restrict__ x, const float* __restrict__ w,
    const float* __restrict__ bias, float* __restrict__ ssq,
    float* __restrict__ attn)
{
    const int tile = blockIdx.x, h = blockIdx.y, b = blockIdx.z;
    const int y0  = tile * 4;
    const int tid = threadIdx.x;
    const int ch  = tid >> 3, q8 = tid & 7;
    const int lane = tid & 63, wv = tid >> 6;
    const int m = lane & 31, hf = lane >> 5;

    __shared__ float xs[2 * 12 * 6 * 40];         // q half then k half, fp32
    __shared__ unsigned short qs[16 * 32 * 8];    // [g][ch][8] bf16 frags
    __shared__ unsigned short ks[16 * 32 * 8];

    const int gq0 = (h * 32) / 3;
    const int ncq = (h * 32 + 31) / 3 - gq0 + 1;  // 11 or 12
    const int gl  = (h * 32 + ch) / 3 - gq0;      // this thread's staged channel

    const int ocq = h * HD + ch;
    float wq[9], wk[9];
#pragma unroll
    for (int t = 0; t < 9; ++t) {
        wq[t] = w[(size_t)ocq * 9 + t];
        wk[t] = w[(size_t)(Cc + ocq) * 9 + t];
    }
    const float bq = bias[ocq], bk = bias[Cc + ocq];

    // ---- hoisted stage decomposition: 2 tensors x 12 ch x 6 rows x 10 c4 ----
    const float* srcp[6];
    int dsto[6], colb[6];
#pragma unroll
    for (int j = 0; j < 6; ++j) {
        int i = tid + 256 * j;
        if (i < 1440) {
            int t   = i / 720;
            int jj  = i - t * 720;
            int c   = jj / 60;
            int rem = jj - c * 60;
            int r   = rem / 10;
            int c4  = rem - r * 10;
            int cg  = (c < ncq) ? c : (ncq - 1);
            int gch = t * 64 + gq0 + cg;
            int y   = y0 - 1 + r;
            srcp[j] = (y >= 0 && y < H)
                    ? x + ((size_t)b * Cc + gch) * HW + (size_t)y * Wd : nullptr;
            dsto[j] = t * 2880 + (c * 6 + r) * 40 + c4 * 4;
            colb[j] = c4 * 4 - 4;
        } else {
            srcp[j] = nullptr; dsto[j] = -1; colb[j] = 0;
        }
    }

    f32x16 acc;
#pragma unroll
    for (int i = 0; i < 16; ++i) acc[i] = 0.f;
    float ssq_a = 0.f, ssk_a = 0.f;

    float4 pf[6];
    fetch_strip(srcp, colb, 0, pf);               // prologue prefetch

#pragma unroll 1
    for (int s = 0; s < 4; ++s) {
        // write prefetched strip into LDS (waits vmcnt on pf automatically)
#pragma unroll
        for (int j = 0; j < 6; ++j)
            if (dsto[j] >= 0) *(float4*)&xs[dsto[j]] = pf[j];
        __syncthreads();   // xs ready AND prior MFMA done (qs/ks free)

        if (s < 3) fetch_strip(srcp, colb, s + 1, pf);   // hide under conv

        ssq_a += conv_lds(xs + gl * 240, wq, bq, q8, ch, qs);
        ssk_a += conv_lds(xs + 2880 + gl * 240, wk, bk, q8, ch, ks);
        __syncthreads();   // frags ready; xs fully consumed

        // Gram: wave wv handles MFMAs (wv*2+cc), granule = (wv*2+cc)*2+hf
#pragma unroll
        for (int cc = 0; cc < 2; ++cc) {
            int g = (wv * 2 + cc) * 2 + hf;
            s16x8 qa = *(const s16x8*)&qs[(g * 32 + m) << 3];
            s16x8 kb = *(const s16x8*)&ks[(g * 32 + m) << 3];
            acc = __builtin_amdgcn_mfma_f32_32x32x16_bf16(qa, kb, acc, 0, 0, 0);
        }
    }

    // reduce 4 waves' Gram partials in LDS, one global atomic pass
    __syncthreads();
    float* sacc = (float*)qs;
    for (int i = tid; i < 1024; i += 256) sacc[i] = 0.f;
    __syncthreads();
#pragma unroll
    for (int r = 0; r < 16; ++r) {
        int row = (r & 3) + 8 * (r >> 2) + 4 * hf;
        atomicAdd(&sacc[row * 32 + m], acc[r]);
    }
    __syncthreads();
    float* ap = attn + (size_t)(b * NH + h) * 1024;
    for (int i = tid; i < 1024; i += 256) atomicAdd(&ap[i], sacc[i]);

    // per-channel sum-of-squares: 8 threads per channel are contiguous lanes
    for (int off = 4; off; off >>= 1) {
        ssq_a += __shfl_down(ssq_a, off, 8);
        ssk_a += __shfl_down(ssk_a, off, 8);
    }
    if (q8 == 0) {
        atomicAdd(&ssq[b * Cc + ocq], ssq_a);
        atomicAdd(&ssq[B * Cc + b * Cc + ocq], ssk_a);
    }
}

// ---------------------------------------------------------------------------
// K1b: grouped 3x3 conv for v only (input groups 128..191, 3 outputs each).
// Same structure as the proven round-0 conv kernel. grid: (8, 64, 8).
// ---------------------------------------------------------------------------
constexpr int TS = 16;

__global__ __launch_bounds__(256) void conv_v(
    const float* __restrict__ x, const float* __restrict__ w,
    const float* __restrict__ bias, unsigned short* __restrict__ vws)
{
    int tile = blockIdx.x;
    int gv   = blockIdx.y;          // 0..63
    int b    = blockIdx.z;
    int y0   = tile * TS;

    __shared__ float sm[TS + 2][132];

    const float* xp = x + ((size_t)b * Cc + 128 + gv) * HW;
    for (int i = threadIdx.x; i < (TS + 2) * 32; i += 256) {
        int r = i >> 5, c4 = (i & 31) * 4;
        int y = y0 - 1 + r;
        if (y >= 0 && y < H) {
            float4 v4 = *(const float4*)(xp + (size_t)y * Wd + c4);
            sm[r][c4 + 1] = v4.x; sm[r][c4 + 2] = v4.y;
            sm[r][c4 + 3] = v4.z; sm[r][c4 + 4] = v4.w;
        } else {
            sm[r][c4 + 1] = 0.f; sm[r][c4 + 2] = 0.f;
            sm[r][c4 + 3] = 0.f; sm[r][c4 + 4] = 0.f;
        }
    }
    for (int i = threadIdx.x; i < (TS + 2) * 2; i += 256) {
        int r = i >> 1;
        sm[r][(i & 1) ? 129 : 0] = 0.f;
    }
    __syncthreads();

    float wreg[3][9], breg[3];
    for (int j = 0; j < 3; ++j) {
        const float* wp = w + (size_t)(2 * Cc + 3 * gv + j) * 9;
#pragma unroll
        for (int t = 0; t < 9; ++t) wreg[j][t] = wp[t];
        breg[j] = bias[2 * Cc + 3 * gv + j];
    }

    int xq = (threadIdx.x & 31) * 4;
    int ys = threadIdx.x >> 5;

    for (int yy = ys; yy < TS; yy += 8) {
        float rvv[3][6];
        for (int r = 0; r < 3; ++r) {
            float4 a4 = *(const float4*)&sm[yy + r][xq];
            float2 a2 = *(const float2*)&sm[yy + r][xq + 4];
            rvv[r][0] = a4.x; rvv[r][1] = a4.y; rvv[r][2] = a4.z;
            rvv[r][3] = a4.w; rvv[r][4] = a2.x; rvv[r][5] = a2.y;
        }
        for (int j = 0; j < 3; ++j) {
            unsigned short pk[4];
            for (int xx = 0; xx < 4; ++xx) {
                float s = breg[j]
                    + wreg[j][0] * rvv[0][xx] + wreg[j][1] * rvv[0][xx + 1] + wreg[j][2] * rvv[0][xx + 2]
                    + wreg[j][3] * rvv[1][xx] + wreg[j][4] * rvv[1][xx + 1] + wreg[j][5] * rvv[1][xx + 2]
                    + wreg[j][6] * rvv[2][xx] + wreg[j][7] * rvv[2][xx + 1] + wreg[j][8] * rvv[2][xx + 2];
                pk[xx] = f2bf(s);
            }
            unsigned short* op = vws + ((size_t)b * Cc + 3 * gv + j) * HW
                                     + (size_t)(y0 + yy) * Wd + xq;
            *(ushort4*)op = make_ushort4(pk[0], pk[1], pk[2], pk[3]);
        }
    }
}

// ---------------------------------------------------------------------------
// K2b: scale by 1/(||q_c|| ||k_d||) * temperature[h], softmax over d.
// ---------------------------------------------------------------------------
__global__ void softmax_attn(float* __restrict__ attn,
                             const float* __restrict__ ssq,
                             const float* __restrict__ temp)
{
    int h = blockIdx.x % NH, b = blockIdx.x / NH;
    __shared__ float nk[32];
    if (threadIdx.x < 32)
        nk[threadIdx.x] = fmaxf(sqrtf(ssq[B * Cc + b * Cc + h * 32 + threadIdx.x]), 1e-12f);
    __syncthreads();
    int c = threadIdx.x;
    if (c >= 32) return;
    float nq = fmaxf(sqrtf(ssq[b * Cc + h * 32 + c]), 1e-12f);
    float t = temp[h];
    float* ap = attn + ((size_t)(b * NH + h) * 32 + c) * 32;
    float row[32];
    float mx = -1e30f;
    for (int d = 0; d < 32; ++d) {
        float v = ap[d] / (nq * nk[d]) * t;
        row[d] = v;
        mx = fmaxf(mx, v);
    }
    float sum = 0.f;
    for (int d = 0; d < 32; ++d) { row[d] = expf(row[d] - mx); sum += row[d]; }
    float inv = 1.f / sum;
    for (int d = 0; d < 32; ++d) ap[d] = row[d] * inv;
}

// ---------------------------------------------------------------------------
// K3a: M[b][o][c=h*32+d] = sum_{c'} w_out[o][h*32+c'] * attn[b][h][c'][d], bf16.
// ---------------------------------------------------------------------------
__global__ __launch_bounds__(256) void make_m(
    const float* __restrict__ attn, const float* __restrict__ w_out,
    unsigned short* __restrict__ M)
{
    int h = blockIdx.x, b = blockIdx.y;
    __shared__ float as[32][33];
    for (int i = threadIdx.x; i < 1024; i += 256)
        as[i / 32][i % 32] = attn[(size_t)((b * NH + h) * 32 + i / 32) * 32 + i % 32];
    __syncthreads();
    for (int i = threadIdx.x; i < Cc * 32; i += 256) {
        int o = i / 32, d = i % 32;
        const float* wp = w_out + (size_t)o * Cc + h * 32;
        float s = 0.f;
        for (int cp = 0; cp < 32; ++cp) s += wp[cp] * as[cp][d];
        M[((size_t)b * Cc + o) * Cc + h * 32 + d] = f2bf(s);
    }
}

// ---------------------------------------------------------------------------
// K3b: out[b][o][n] = sum_c M[o][c] * v[c][n] + b_out[o] via MFMA 32x32x16.
// Block tile: o=192 (all) x n=128; 4 waves = 2(m) x 2(n); wave: 96o x 64n.
// v transposed through LDS; next k-step's v loads prefetched into registers
// during the MFMA phase (T14). grid: (128, 8).
// ---------------------------------------------------------------------------
constexpr int BN = 128;

__global__ __launch_bounds__(256) void out_gemm(
    const unsigned short* __restrict__ vws, const unsigned short* __restrict__ M,
    const float* __restrict__ b_out, float* __restrict__ out)
{
    int n0 = blockIdx.x * BN;
    int b  = blockIdx.y;

    const unsigned short* vp = vws + (size_t)b * Cc * HW;
    const unsigned short* mp = M + (size_t)b * Cc * Cc;

    __shared__ unsigned short vsT[BN][24];   // 16 used, stride 24 (48B, b128-aligned)

    int tid  = threadIdx.x;
    int lane = tid & 63, wv = tid >> 6;
    int wm = wv & 1, wn = wv >> 1;
    int col = lane & 31, half = lane >> 5;

    f32x16 acc[6];
    for (int t = 0; t < 6; ++t)
        for (int i = 0; i < 16; ++i) acc[t][i] = 0.f;

    int p  = tid >> 5;   // 0..7 channel-pair
    int nq = tid & 31;   // 0..31 n-quad

    // prologue prefetch (k0 = 0)
    const unsigned short* s0 = vp + (size_t)(2 * p) * HW + n0 + 4 * nq;
    ushort4 va = *(const ushort4*)s0;
    ushort4 vb = *(const ushort4*)(s0 + HW);

    for (int k0 = 0; k0 < Cc; k0 += 16) {
        *(unsigned int*)&vsT[4 * nq + 0][2 * p] = (unsigned int)va.x | ((unsigned int)vb.x << 16);
        *(unsigned int*)&vsT[4 * nq + 1][2 * p] = (unsigned int)va.y | ((unsigned int)vb.y << 16);
        *(unsigned int*)&vsT[4 * nq + 2][2 * p] = (unsigned int)va.z | ((unsigned int)vb.z << 16);
        *(unsigned int*)&vsT[4 * nq + 3][2 * p] = (unsigned int)va.w | ((unsigned int)vb.w << 16);
        __syncthreads();

        // prefetch next k-step's v while this step's MFMAs run
        ushort4 va2 = make_ushort4(0, 0, 0, 0), vb2 = va2;
        if (k0 + 16 < Cc) {
            const unsigned short* s1 = vp + (size_t)(k0 + 16 + 2 * p) * HW + n0 + 4 * nq;
            va2 = *(const ushort4*)s1;
            vb2 = *(const ushort4*)(s1 + HW);
        }

        s16x8 af[3], bf[2];
        for (int mt = 0; mt < 3; ++mt) {
            int o = wm * 96 + mt * 32 + col;
            af[mt] = *(const s16x8*)(mp + (size_t)o * Cc + k0 + half * 8);
        }
        for (int nt = 0; nt < 2; ++nt) {
            int nn = wn * 64 + nt * 32 + col;
            bf[nt] = *(const s16x8*)&vsT[nn][half * 8];
        }
        for (int mt = 0; mt < 3; ++mt)
            for (int nt = 0; nt < 2; ++nt)
                acc[mt * 2 + nt] = __builtin_amdgcn_mfma_f32_32x32x16_bf16(
                    af[mt], bf[nt], acc[mt * 2 + nt], 0, 0, 0);
        __syncthreads();
        va = va2; vb = vb2;
    }

    for (int mt = 0; mt < 3; ++mt)
        for (int nt = 0; nt < 2; ++nt) {
            f32x16 c = acc[mt * 2 + nt];
            int n = n0 + wn * 64 + nt * 32 + col;
            for (int r = 0; r < 16; ++r) {
                int row = (r & 3) + 8 * (r >> 2) + 4 * half;
                int o = wm * 96 + mt * 32 + row;
                out[((size_t)b * Cc + o) * HW + n] = c[r] + b_out[o];
            }
        }
}

extern "C" void kernel_launch(void* const* d_in, const int* in_sizes, int n_in,
                              void* d_out, int out_size, void* d_ws, size_t ws_size,
                              hipStream_t stream) {
    const float* x      = (const float*)d_in[0];
    const float* w_qkv  = (const float*)d_in[1];
    const float* b_qkv  = (const float*)d_in[2];
    const float* temp   = (const float*)d_in[3];
    const float* w_out  = (const float*)d_in[4];
    const float* b_out  = (const float*)d_in[5];
    float* out = (float*)d_out;

    char* ws = (char*)d_ws;
    unsigned short* vws = (unsigned short*)(ws + OFF_V);
    float* attn         = (float*)(ws + OFF_ATTN);
    float* ssq          = (float*)(ws + OFF_SSQ);
    unsigned short* M   = (unsigned short*)(ws + OFF_M);

    zero_kernel<<<(N_ZERO + 255) / 256, 256, 0, stream>>>(attn, N_ZERO);
    fused_conv_qk<<<dim3(H / 4, NH, B), 256, 0, stream>>>(x, w_qkv, b_qkv, ssq, attn);
    conv_v<<<dim3(H / TS, 64, B), 256, 0, stream>>>(x, w_qkv, b_qkv, vws);
    softmax_attn<<<B * NH, 64, 0, stream>>>(attn, ssq, temp);
    make_m<<<dim3(NH, B), 256, 0, stream>>>(attn, w_out, M);
    out_gemm<<<dim3(HW / BN, B), 256, 0, stream>>>(vws, M, b_out, out);
}

// Round 4
// 292.664 us; speedup vs baseline: 1.3080x; 1.3080x over previous
//
#include <hip/hip_runtime.h>
#include <hip/hip_bf16.h>

// Problem constants: B=8, C=192, H=W=128, NH=6, HD=32, N=16384
constexpr int B   = 8;
constexpr int Cc  = 192;
constexpr int H   = 128;
constexpr int Wd  = 128;
constexpr int NH  = 6;
constexpr int HD  = 32;           // channels per head
constexpr int HW  = H * Wd;       // 16384

typedef short s16x8 __attribute__((ext_vector_type(8)));
typedef float f32x16 __attribute__((ext_vector_type(16)));

// Workspace layout (bytes):
//   v    : [B][192][HW] bf16           =  50,331,648
//   attn : [B][NH][32][32] fp32        =     196,608
//   ssq  : [2][B][Cc] fp32 (q then k)  =      12,288
//   zero : 256 B (OOB source for global_load_lds)
//   M    : [B][192][192] bf16 ([o][c]) =     589,824
constexpr size_t OFF_V    = 0;
constexpr size_t OFF_ATTN = 50331648ULL;
constexpr size_t OFF_SSQ  = OFF_ATTN + 196608ULL;
constexpr size_t OFF_ZERO = OFF_SSQ + 12288ULL;
constexpr size_t OFF_M    = OFF_ZERO + 256ULL;
constexpr int    N_ZERO   = (196608 + 12288 + 256) / 4;   // attn+ssq+zero floats

__device__ inline unsigned short f2bf(float f) {
    __hip_bfloat16 h = __float2bfloat16(f);
    return *(unsigned short*)&h;
}

__global__ void zero_kernel(float* __restrict__ p, int n) {
    int i = blockIdx.x * 256 + threadIdx.x;
    if (i < n) p[i] = 0.f;
}

#define AS1C(p) ((const __attribute__((address_space(1))) void*)(p))
#define AS3(p)  ((__attribute__((address_space(3))) void*)(p))

// ---------------------------------------------------------------------------
// K1a: fused grouped-3x3-conv (q,k) + channel-Gram (q@k^T) per (b,h,4-row tile).
// Pipelined via global_load_lds (no VGPR round-trip -> no spill): strip s+1's
// DMA is issued at the top of strip s's conv phase into the other xs buffer;
// HBM latency hides under ~2000cy of conv VALU. OOB lanes read a zeroed
// workspace region. grid: (H/4=32, NH, B), block 256 = 32 ch x 8 col-quads.
// LDS: 2x22.5KB xs dbuf + 2x8KB frags = 62.5KB -> 2 blocks/CU.
// ---------------------------------------------------------------------------

// read 6 conv-window floats (cols 4q8+3 .. 4q8+8 of a 40-float LDS row)
__device__ __forceinline__ void ld6(const float* __restrict__ base, int r,
                                    int q8, float (&e)[6]) {
    const float* p = base + r * 40 + q8 * 4;     // 16B aligned
    float4 a = *(const float4*)p;
    float4 bq = *(const float4*)(p + 4);
    float2 cd = *(const float2*)(p + 8);
    e[0] = a.w; e[1] = bq.x; e[2] = bq.y; e[3] = bq.z; e[4] = bq.w; e[5] = cd.x;
}

// 4-row x 4-col conv for one output channel from staged LDS; pack bf16x4 into
// fragment-native frag[g=4y+(q8>>1)][ch][8]. Returns sum of squares.
__device__ __forceinline__ float conv_lds(
    const float* __restrict__ base, const float (&wr)[9], float br,
    int q8, int ch, unsigned short* __restrict__ frag)
{
    float rv[3][6];
    ld6(base, 0, q8, rv[0]);
    ld6(base, 1, q8, rv[1]);
    float ss = 0.f;
#pragma unroll
    for (int y = 0; y < 4; ++y) {
        ld6(base, y + 2, q8, rv[(y + 2) % 3]);
        const float* r0 = rv[y % 3];
        const float* r1 = rv[(y + 1) % 3];
        const float* r2 = rv[(y + 2) % 3];
        float o[4];
#pragma unroll
        for (int xx = 0; xx < 4; ++xx) {
            o[xx] = br
                + wr[0] * r0[xx] + wr[1] * r0[xx + 1] + wr[2] * r0[xx + 2]
                + wr[3] * r1[xx] + wr[4] * r1[xx + 1] + wr[5] * r1[xx + 2]
                + wr[6] * r2[xx] + wr[7] * r2[xx + 1] + wr[8] * r2[xx + 2];
        }
        ss += o[0] * o[0] + o[1] * o[1] + o[2] * o[2] + o[3] * o[3];
        ushort4 pk = make_ushort4(f2bf(o[0]), f2bf(o[1]), f2bf(o[2]), f2bf(o[3]));
        int g = 4 * y + (q8 >> 1);
        *(ushort4*)(frag + ((g * 32 + ch) << 3) + ((q8 & 1) << 2)) = pk;
    }
    return ss;
}

__global__ __launch_bounds__(256, 2) void fused_conv_qk(
    const float* __restrict__ x, const float* __restrict__ w,
    const float* __restrict__ bias, float* __restrict__ ssq,
    float* __restrict__ attn, const float* __restrict__ zbuf)
{
    const int tile = blockIdx.x, h = blockIdx.y, b = blockIdx.z;
    const int y0  = tile * 4;
    const int tid = threadIdx.x;
    const int ch  = tid >> 3, q8 = tid & 7;
    const int lane = tid & 63, wv = tid >> 6;
    const int m = lane & 31, hf = lane >> 5;

    __shared__ float xs[2][5760];                 // dbuf: [q 2880 | k 2880]
    __shared__ unsigned short qs[16 * 32 * 8];    // [g][ch][8] bf16 frags
    __shared__ unsigned short ks[16 * 32 * 8];

    const int gq0 = (h * 32) / 3;
    const int ncq = (h * 32 + 31) / 3 - gq0 + 1;  // 11 or 12
    const int gl  = (h * 32 + ch) / 3 - gq0;      // this thread's staged channel

    const int ocq = h * HD + ch;
    float wq[9], wk[9];
#pragma unroll
    for (int t = 0; t < 9; ++t) {
        wq[t] = w[(size_t)ocq * 9 + t];
        wk[t] = w[(size_t)(Cc + ocq) * 9 + t];
    }
    const float bq = bias[ocq], bk = bias[Cc + ocq];

    // ---- hoisted stage decomposition: item i = tid + 256j over
    //      2 tensors x 12 ch x 6 rows x 10 float4; LDS dst = item*16B ----
    const float* sp[6];     // row base (nullptr if y out of range)
    int cb[6];              // column base offset (c4*4 - 4)
    int i4[6];              // float index in xs buffer (= item*4)
    bool act[6];
#pragma unroll
    for (int j = 0; j < 6; ++j) {
        int i = tid + 256 * j;
        act[j] = (i < 1440);
        if (act[j]) {
            int t   = i / 720;
            int jj  = i - t * 720;
            int c   = jj / 60;
            int rem = jj - c * 60;
            int r   = rem / 10;
            int c4  = rem - r * 10;
            int cg  = (c < ncq) ? c : (ncq - 1);
            int gch = t * 64 + gq0 + cg;
            int y   = y0 - 1 + r;
            sp[j] = (y >= 0 && y < H)
                  ? x + ((size_t)b * Cc + gch) * HW + (size_t)y * Wd : nullptr;
            cb[j] = c4 * 4 - 4;
            i4[j] = i * 4;
        } else { sp[j] = nullptr; cb[j] = 0; i4[j] = 0; }
    }

    f32x16 acc;
#pragma unroll
    for (int i = 0; i < 16; ++i) acc[i] = 0.f;
    float ssq_a = 0.f, ssk_a = 0.f;

    // prologue DMA: strip 0 -> xs[0]
#pragma unroll
    for (int j = 0; j < 6; ++j) {
        if (!act[j]) continue;
        int col = cb[j];
        const float* src = (sp[j] != nullptr && (unsigned)col <= 124u)
                         ? sp[j] + col : zbuf;
        __builtin_amdgcn_global_load_lds(AS1C(src), AS3(&xs[0][i4[j]]), 16, 0, 0);
    }

#pragma unroll 1
    for (int s = 0; s < 4; ++s) {
        float* cur = xs[s & 1];
        __syncthreads();   // strip-s DMA landed (vmcnt drain); qs/ks free

        if (s < 3) {       // issue strip s+1 DMA; hides under conv below
            float* nxt = xs[(s + 1) & 1];
#pragma unroll
            for (int j = 0; j < 6; ++j) {
                if (!act[j]) continue;
                int col = (s + 1) * 32 + cb[j];
                const float* src = (sp[j] != nullptr && (unsigned)col <= 124u)
                                 ? sp[j] + col : zbuf;
                __builtin_amdgcn_global_load_lds(AS1C(src), AS3(&nxt[i4[j]]), 16, 0, 0);
            }
        }

        ssq_a += conv_lds(cur + gl * 240, wq, bq, q8, ch, qs);
        ssk_a += conv_lds(cur + 2880 + gl * 240, wk, bk, q8, ch, ks);
        __syncthreads();   // frags ready; xs[cur] fully consumed

        // Gram: wave wv handles MFMAs (wv*2+cc), granule = (wv*2+cc)*2+hf
#pragma unroll
        for (int cc = 0; cc < 2; ++cc) {
            int g = (wv * 2 + cc) * 2 + hf;
            s16x8 qa = *(const s16x8*)&qs[(g * 32 + m) << 3];
            s16x8 kb = *(const s16x8*)&ks[(g * 32 + m) << 3];
            acc = __builtin_amdgcn_mfma_f32_32x32x16_bf16(qa, kb, acc, 0, 0, 0);
        }
    }

    // reduce 4 waves' Gram partials in LDS, one global atomic pass
    __syncthreads();
    float* sacc = (float*)qs;
    for (int i = tid; i < 1024; i += 256) sacc[i] = 0.f;
    __syncthreads();
#pragma unroll
    for (int r = 0; r < 16; ++r) {
        int row = (r & 3) + 8 * (r >> 2) + 4 * hf;
        atomicAdd(&sacc[row * 32 + m], acc[r]);
    }
    __syncthreads();
    float* ap = attn + (size_t)(b * NH + h) * 1024;
    for (int i = tid; i < 1024; i += 256) atomicAdd(&ap[i], sacc[i]);

    // per-channel sum-of-squares: 8 threads per channel are contiguous lanes
    for (int off = 4; off; off >>= 1) {
        ssq_a += __shfl_down(ssq_a, off, 8);
        ssk_a += __shfl_down(ssk_a, off, 8);
    }
    if (q8 == 0) {
        atomicAdd(&ssq[b * Cc + ocq], ssq_a);
        atomicAdd(&ssq[B * Cc + b * Cc + ocq], ssk_a);
    }
}

// ---------------------------------------------------------------------------
// K1b: grouped 3x3 conv for v only (input groups 128..191, 3 outputs each).
// Same structure as the proven round-0 conv kernel. grid: (8, 64, 8).
// ---------------------------------------------------------------------------
constexpr int TS = 16;

__global__ __launch_bounds__(256) void conv_v(
    const float* __restrict__ x, const float* __restrict__ w,
    const float* __restrict__ bias, unsigned short* __restrict__ vws)
{
    int tile = blockIdx.x;
    int gv   = blockIdx.y;          // 0..63
    int b    = blockIdx.z;
    int y0   = tile * TS;

    __shared__ float sm[TS + 2][132];

    const float* xp = x + ((size_t)b * Cc + 128 + gv) * HW;
    for (int i = threadIdx.x; i < (TS + 2) * 32; i += 256) {
        int r = i >> 5, c4 = (i & 31) * 4;
        int y = y0 - 1 + r;
        if (y >= 0 && y < H) {
            float4 v4 = *(const float4*)(xp + (size_t)y * Wd + c4);
            sm[r][c4 + 1] = v4.x; sm[r][c4 + 2] = v4.y;
            sm[r][c4 + 3] = v4.z; sm[r][c4 + 4] = v4.w;
        } else {
            sm[r][c4 + 1] = 0.f; sm[r][c4 + 2] = 0.f;
            sm[r][c4 + 3] = 0.f; sm[r][c4 + 4] = 0.f;
        }
    }
    for (int i = threadIdx.x; i < (TS + 2) * 2; i += 256) {
        int r = i >> 1;
        sm[r][(i & 1) ? 129 : 0] = 0.f;
    }
    __syncthreads();

    float wreg[3][9], breg[3];
    for (int j = 0; j < 3; ++j) {
        const float* wp = w + (size_t)(2 * Cc + 3 * gv + j) * 9;
#pragma unroll
        for (int t = 0; t < 9; ++t) wreg[j][t] = wp[t];
        breg[j] = bias[2 * Cc + 3 * gv + j];
    }

    int xq = (threadIdx.x & 31) * 4;
    int ys = threadIdx.x >> 5;

    for (int yy = ys; yy < TS; yy += 8) {
        float rvv[3][6];
        for (int r = 0; r < 3; ++r) {
            float4 a4 = *(const float4*)&sm[yy + r][xq];
            float2 a2 = *(const float2*)&sm[yy + r][xq + 4];
            rvv[r][0] = a4.x; rvv[r][1] = a4.y; rvv[r][2] = a4.z;
            rvv[r][3] = a4.w; rvv[r][4] = a2.x; rvv[r][5] = a2.y;
        }
        for (int j = 0; j < 3; ++j) {
            unsigned short pk[4];
            for (int xx = 0; xx < 4; ++xx) {
                float s = breg[j]
                    + wreg[j][0] * rvv[0][xx] + wreg[j][1] * rvv[0][xx + 1] + wreg[j][2] * rvv[0][xx + 2]
                    + wreg[j][3] * rvv[1][xx] + wreg[j][4] * rvv[1][xx + 1] + wreg[j][5] * rvv[1][xx + 2]
                    + wreg[j][6] * rvv[2][xx] + wreg[j][7] * rvv[2][xx + 1] + wreg[j][8] * rvv[2][xx + 2];
                pk[xx] = f2bf(s);
            }
            unsigned short* op = vws + ((size_t)b * Cc + 3 * gv + j) * HW
                                     + (size_t)(y0 + yy) * Wd + xq;
            *(ushort4*)op = make_ushort4(pk[0], pk[1], pk[2], pk[3]);
        }
    }
}

// ---------------------------------------------------------------------------
// K2b: scale by 1/(||q_c|| ||k_d||) * temperature[h], softmax over d.
// ---------------------------------------------------------------------------
__global__ void softmax_attn(float* __restrict__ attn,
                             const float* __restrict__ ssq,
                             const float* __restrict__ temp)
{
    int h = blockIdx.x % NH, b = blockIdx.x / NH;
    __shared__ float nk[32];
    if (threadIdx.x < 32)
        nk[threadIdx.x] = fmaxf(sqrtf(ssq[B * Cc + b * Cc + h * 32 + threadIdx.x]), 1e-12f);
    __syncthreads();
    int c = threadIdx.x;
    if (c >= 32) return;
    float nq = fmaxf(sqrtf(ssq[b * Cc + h * 32 + c]), 1e-12f);
    float t = temp[h];
    float* ap = attn + ((size_t)(b * NH + h) * 32 + c) * 32;
    float row[32];
    float mx = -1e30f;
    for (int d = 0; d < 32; ++d) {
        float v = ap[d] / (nq * nk[d]) * t;
        row[d] = v;
        mx = fmaxf(mx, v);
    }
    float sum = 0.f;
    for (int d = 0; d < 32; ++d) { row[d] = expf(row[d] - mx); sum += row[d]; }
    float inv = 1.f / sum;
    for (int d = 0; d < 32; ++d) ap[d] = row[d] * inv;
}

// ---------------------------------------------------------------------------
// K3a: M[b][o][c=h*32+d] = sum_{c'} w_out[o][h*32+c'] * attn[b][h][c'][d], bf16.
// ---------------------------------------------------------------------------
__global__ __launch_bounds__(256) void make_m(
    const float* __restrict__ attn, const float* __restrict__ w_out,
    unsigned short* __restrict__ M)
{
    int h = blockIdx.x, b = blockIdx.y;
    __shared__ float as[32][33];
    for (int i = threadIdx.x; i < 1024; i += 256)
        as[i / 32][i % 32] = attn[(size_t)((b * NH + h) * 32 + i / 32) * 32 + i % 32];
    __syncthreads();
    for (int i = threadIdx.x; i < Cc * 32; i += 256) {
        int o = i / 32, d = i % 32;
        const float* wp = w_out + (size_t)o * Cc + h * 32;
        float s = 0.f;
        for (int cp = 0; cp < 32; ++cp) s += wp[cp] * as[cp][d];
        M[((size_t)b * Cc + o) * Cc + h * 32 + d] = f2bf(s);
    }
}

// ---------------------------------------------------------------------------
// K3b: out[b][o][n] = sum_c M[o][c] * v[c][n] + b_out[o] via MFMA 32x32x16.
// Block tile: o=192 (all) x n=128; 4 waves = 2(m) x 2(n); wave: 96o x 64n.
// v transposed through LDS; next k-step's v loads prefetched into registers
// during the MFMA phase (T14). grid: (128, 8).
// ---------------------------------------------------------------------------
constexpr int BN = 128;

__global__ __launch_bounds__(256) void out_gemm(
    const unsigned short* __restrict__ vws, const unsigned short* __restrict__ M,
    const float* __restrict__ b_out, float* __restrict__ out)
{
    int n0 = blockIdx.x * BN;
    int b  = blockIdx.y;

    const unsigned short* vp = vws + (size_t)b * Cc * HW;
    const unsigned short* mp = M + (size_t)b * Cc * Cc;

    __shared__ unsigned short vsT[BN][24];   // 16 used, stride 24 (48B, b128-aligned)

    int tid  = threadIdx.x;
    int lane = tid & 63, wv = tid >> 6;
    int wm = wv & 1, wn = wv >> 1;
    int col = lane & 31, half = lane >> 5;

    f32x16 acc[6];
    for (int t = 0; t < 6; ++t)
        for (int i = 0; i < 16; ++i) acc[t][i] = 0.f;

    int p  = tid >> 5;   // 0..7 channel-pair
    int nq = tid & 31;   // 0..31 n-quad

    // prologue prefetch (k0 = 0)
    const unsigned short* s0 = vp + (size_t)(2 * p) * HW + n0 + 4 * nq;
    ushort4 va = *(const ushort4*)s0;
    ushort4 vb = *(const ushort4*)(s0 + HW);

    for (int k0 = 0; k0 < Cc; k0 += 16) {
        *(unsigned int*)&vsT[4 * nq + 0][2 * p] = (unsigned int)va.x | ((unsigned int)vb.x << 16);
        *(unsigned int*)&vsT[4 * nq + 1][2 * p] = (unsigned int)va.y | ((unsigned int)vb.y << 16);
        *(unsigned int*)&vsT[4 * nq + 2][2 * p] = (unsigned int)va.z | ((unsigned int)vb.z << 16);
        *(unsigned int*)&vsT[4 * nq + 3][2 * p] = (unsigned int)va.w | ((unsigned int)vb.w << 16);
        __syncthreads();

        // prefetch next k-step's v while this step's MFMAs run
        ushort4 va2 = make_ushort4(0, 0, 0, 0), vb2 = va2;
        if (k0 + 16 < Cc) {
            const unsigned short* s1 = vp + (size_t)(k0 + 16 + 2 * p) * HW + n0 + 4 * nq;
            va2 = *(const ushort4*)s1;
            vb2 = *(const ushort4*)(s1 + HW);
        }

        s16x8 af[3], bf[2];
        for (int mt = 0; mt < 3; ++mt) {
            int o = wm * 96 + mt * 32 + col;
            af[mt] = *(const s16x8*)(mp + (size_t)o * Cc + k0 + half * 8);
        }
        for (int nt = 0; nt < 2; ++nt) {
            int nn = wn * 64 + nt * 32 + col;
            bf[nt] = *(const s16x8*)&vsT[nn][half * 8];
        }
        for (int mt = 0; mt < 3; ++mt)
            for (int nt = 0; nt < 2; ++nt)
                acc[mt * 2 + nt] = __builtin_amdgcn_mfma_f32_32x32x16_bf16(
                    af[mt], bf[nt], acc[mt * 2 + nt], 0, 0, 0);
        __syncthreads();
        va = va2; vb = vb2;
    }

    for (int mt = 0; mt < 3; ++mt)
        for (int nt = 0; nt < 2; ++nt) {
            f32x16 c = acc[mt * 2 + nt];
            int n = n0 + wn * 64 + nt * 32 + col;
            for (int r = 0; r < 16; ++r) {
                int row = (r & 3) + 8 * (r >> 2) + 4 * half;
                int o = wm * 96 + mt * 32 + row;
                out[((size_t)b * Cc + o) * HW + n] = c[r] + b_out[o];
            }
        }
}

extern "C" void kernel_launch(void* const* d_in, const int* in_sizes, int n_in,
                              void* d_out, int out_size, void* d_ws, size_t ws_size,
                              hipStream_t stream) {
    const float* x      = (const float*)d_in[0];
    const float* w_qkv  = (const float*)d_in[1];
    const float* b_qkv  = (const float*)d_in[2];
    const float* temp   = (const float*)d_in[3];
    const float* w_out  = (const float*)d_in[4];
    const float* b_out  = (const float*)d_in[5];
    float* out = (float*)d_out;

    char* ws = (char*)d_ws;
    unsigned short* vws = (unsigned short*)(ws + OFF_V);
    float* attn         = (float*)(ws + OFF_ATTN);
    float* ssq          = (float*)(ws + OFF_SSQ);
    const float* zbuf   = (const float*)(ws + OFF_ZERO);
    unsigned short* M   = (unsigned short*)(ws + OFF_M);

    zero_kernel<<<(N_ZERO + 255) / 256, 256, 0, stream>>>(attn, N_ZERO);
    fused_conv_qk<<<dim3(H / 4, NH, B), 256, 0, stream>>>(x, w_qkv, b_qkv, ssq, attn, zbuf);
    conv_v<<<dim3(H / TS, 64, B), 256, 0, stream>>>(x, w_qkv, b_qkv, vws);
    softmax_attn<<<B * NH, 64, 0, stream>>>(attn, ssq, temp);
    make_m<<<dim3(NH, B), 256, 0, stream>>>(attn, w_out, M);
    out_gemm<<<dim3(HW / BN, B), 256, 0, stream>>>(vws, M, b_out, out);
}